// Round 3
// baseline (446.240 us; speedup 1.0000x reference)
//
#include <hip/hip_runtime.h>

typedef __attribute__((ext_vector_type(8))) short short8;
typedef __attribute__((ext_vector_type(4))) float floatx4;

__device__ __forceinline__ unsigned short f2bf(float f) {
    unsigned int x = __float_as_uint(f);
    x = x + 0x7FFFu + ((x >> 16) & 1u);   // RNE
    return (unsigned short)(x >> 16);
}

// ---------------------------------------------------------------------------
// K1: ksum partials over n. k: (128, 1024, 512) fp32, 268 MB stream.
// 1024 blocks: b = blk>>3, c = blk&7 (chunk of 128 n-rows). part[c][b][j] f32.
// ---------------------------------------------------------------------------
__global__ __launch_bounds__(256) void k_reduce(
    const float* __restrict__ kk, float* __restrict__ part)
{
    int blk = blockIdx.x, tid = threadIdx.x;
    int b = blk >> 3, c = blk & 7;
    int f4 = tid & 127;         // float4 column 0..127 (j = f4*4)
    int rh = tid >> 7;          // 0..1
    const float4* base = (const float4*)kk
        + ((size_t)(b * 1024 + c * 128 + rh) * 128 + f4);
    float4 acc = {0.f, 0.f, 0.f, 0.f};
    #pragma unroll 8
    for (int it = 0; it < 64; ++it) {
        float4 v = base[(size_t)it * 256];   // 2 rows = 256 float4
        acc.x += v.x; acc.y += v.y; acc.z += v.z; acc.w += v.w;
    }
    __shared__ float red[2][512];
    red[rh][f4 * 4 + 0] = acc.x;
    red[rh][f4 * 4 + 1] = acc.y;
    red[rh][f4 * 4 + 2] = acc.z;
    red[rh][f4 * 4 + 3] = acc.w;
    __syncthreads();
    for (int j = tid; j < 512; j += 256)
        part[((size_t)(c * 128 + b) << 9) + j] = red[0][j] + red[1][j];
}

// ---------------------------------------------------------------------------
// K2: convert weights fp32 -> bf16 (Wx 1M, Wk 512K, Wo 512K, Wl 4K elems).
// One float4 per thread -> 4 bf16 (uint2 write). 525312 threads = 2052 blocks.
// ---------------------------------------------------------------------------
__global__ __launch_bounds__(256) void k_w2bf(
    const float* __restrict__ Wx, const float* __restrict__ Wk,
    const float* __restrict__ Wo, const float* __restrict__ Wl,
    unsigned short* __restrict__ Wxbf, unsigned short* __restrict__ Wkbf,
    unsigned short* __restrict__ Wobf, unsigned short* __restrict__ Wlbf)
{
    int f = blockIdx.x * 256 + threadIdx.x;   // float4 index
    const float* src; unsigned short* dst; int off;
    if (f < 262144)      { src = Wx; dst = Wxbf; off = f; }
    else if (f < 393216) { src = Wk; dst = Wkbf; off = f - 262144; }
    else if (f < 524288) { src = Wo; dst = Wobf; off = f - 393216; }
    else                 { src = Wl; dst = Wlbf; off = f - 524288; }
    float4 v = ((const float4*)src)[off];
    uint2 o;
    o.x = (unsigned int)f2bf(v.x) | ((unsigned int)f2bf(v.y) << 16);
    o.y = (unsigned int)f2bf(v.z) | ((unsigned int)f2bf(v.w) << 16);
    *(uint2*)(dst + off * 4) = o;
}

// ---------------------------------------------------------------------------
// K3: fused BN1(x fp32) -> xn bf16  AND  combine ksum partials -> ksum bf16
// ---------------------------------------------------------------------------
__global__ __launch_bounds__(256) void k_bn1_combine(
    const float* __restrict__ x, const float* __restrict__ g1,
    const float* __restrict__ b1, const float* __restrict__ part,
    unsigned short* __restrict__ xnbf, unsigned short* __restrict__ ksumbf)
{
    int blk = blockIdx.x, tid = threadIdx.x;
    if (blk < 4) {
        int c = blk * 256 + tid;
        float s = 0.f, ss = 0.f;
        #pragma unroll 8
        for (int b = 0; b < 128; ++b) {
            float v = x[b * 1024 + c];
            s += v; ss += v * v;
        }
        float m  = s * (1.f / 128.f);
        float va = ss * (1.f / 128.f) - m * m;
        float rs = rsqrtf(va + 1e-5f);
        float a  = rs * g1[c];
        float b2 = b1[c] - m * a;
        #pragma unroll 8
        for (int b = 0; b < 128; ++b)
            xnbf[b * 1024 + c] = f2bf(x[b * 1024 + c] * a + b2);
    } else {
        int idx = (blk - 4) * 256 + tid;     // 0..8191
        int b = idx >> 6;
        int j0 = (idx & 63) * 8;
        float s[8];
        #pragma unroll
        for (int u = 0; u < 8; ++u) s[u] = 0.f;
        #pragma unroll
        for (int c = 0; c < 8; ++c) {
            const float4* p = (const float4*)(part + ((size_t)(c * 128 + b) << 9) + j0);
            float4 a0 = p[0], a1 = p[1];
            s[0] += a0.x; s[1] += a0.y; s[2] += a0.z; s[3] += a0.w;
            s[4] += a1.x; s[5] += a1.y; s[6] += a1.z; s[7] += a1.w;
        }
        uint4 v;
        v.x = (unsigned int)f2bf(s[0]) | ((unsigned int)f2bf(s[1]) << 16);
        v.y = (unsigned int)f2bf(s[2]) | ((unsigned int)f2bf(s[3]) << 16);
        v.z = (unsigned int)f2bf(s[4]) | ((unsigned int)f2bf(s[5]) << 16);
        v.w = (unsigned int)f2bf(s[6]) | ((unsigned int)f2bf(s[7]) << 16);
        *(uint4*)(ksumbf + b * 512 + j0) = v;
    }
}

// ---------------------------------------------------------------------------
// MFMA GEMM: C(M,N) = A(M,K) * B(N,K)^T + bscale*bias(N). A,B bf16 row-major.
// One wave per 16x16 tile. A frag A[m=lane&15][k=q*8+j]; B same; D: col=lane&15,
// row=q*4+r (learn_hip m89/m91). bias fp32.
// ---------------------------------------------------------------------------
template <typename OutT>
__global__ __launch_bounds__(256) void k_mfma(
    const unsigned short* __restrict__ A, int lda,
    const unsigned short* __restrict__ B, int ldb,
    const float* __restrict__ bias, float bscale,
    OutT* __restrict__ C, int ldc, int tilesN, int K)
{
    int gid = blockIdx.x * 256 + threadIdx.x;
    int wave = gid >> 6;
    int lane = threadIdx.x & 63;
    int tm = wave / tilesN, tn = wave % tilesN;
    int mn = lane & 15, q = lane >> 4;

    const short8* ap = (const short8*)(A + (size_t)(tm * 16 + mn) * lda + q * 8);
    const short8* bp = (const short8*)(B + (size_t)(tn * 16 + mn) * ldb + q * 8);

    floatx4 acc = {0.f, 0.f, 0.f, 0.f};
    #pragma unroll 4
    for (int k = 0; k < K; k += 32) {
        short8 a = *ap; ap += 4;
        short8 b = *bp; bp += 4;
        acc = __builtin_amdgcn_mfma_f32_16x16x32_bf16(a, b, acc, 0, 0, 0);
    }
    int col = tn * 16 + mn;
    float bv = bias[col] * bscale;
    #pragma unroll
    for (int r = 0; r < 4; ++r) {
        int row = tm * 16 + q * 4 + r;
        float v = acc[r] + bv;
        OutT* dst = C + (size_t)row * ldc + col;
        if constexpr (sizeof(OutT) == 2) *dst = (OutT)f2bf(v);
        else                             *dst = (OutT)v;
    }
}

// ---------------------------------------------------------------------------
// K5: BN2 stats over xq (fp32) viewed as (H*B, 64): scale ab[d], shift ab[64+d]
// ---------------------------------------------------------------------------
__global__ __launch_bounds__(256) void k_bn2(
    const float* __restrict__ xq, const float* __restrict__ g2,
    const float* __restrict__ b2, float* __restrict__ ab)
{
    int d = blockIdx.x, tid = threadIdx.x;
    float s = 0.f, ss = 0.f;
    for (int e = tid; e < 2048; e += 256) {
        int b = e >> 4, h = e & 15;
        float v = xq[b * 1024 + h * 64 + d];
        s += v; ss += v * v;
    }
    __shared__ float r1[256], r2[256];
    r1[tid] = s; r2[tid] = ss;
    __syncthreads();
    for (int off = 128; off; off >>= 1) {
        if (tid < off) { r1[tid] += r1[tid + off]; r2[tid] += r2[tid + off]; }
        __syncthreads();
    }
    if (tid == 0) {
        float m  = r1[0] * (1.f / 2048.f);
        float va = r2[0] * (1.f / 2048.f) - m * m;
        float rs = rsqrtf(va + 1e-5f);
        float a  = rs * g2[d];
        ab[d] = a;
        ab[64 + d] = b2[d] - m * a;
    }
}

// ---------------------------------------------------------------------------
// K6: latent = BN2(xq) @ Wlin^T + blin -> x_hid slot (bf16, B-major layout)
// ---------------------------------------------------------------------------
__global__ __launch_bounds__(256) void k_latent(
    const float* __restrict__ xq, const float* __restrict__ ab,
    const unsigned short* __restrict__ Wlbf, const float* __restrict__ bl,
    unsigned short* __restrict__ xhid)
{
    int tid = threadIdx.x;
    int r = tid >> 6, dp = tid & 63;
    int row = blockIdx.x * 4 + r;     // row = h*128 + b
    int h = row >> 7, b = row & 127;
    __shared__ float xs[4][64];
    xs[r][dp] = xq[b * 1024 + h * 64 + dp] * ab[dp] + ab[64 + dp];
    __syncthreads();
    float dot = bl[dp];
    #pragma unroll 16
    for (int d = 0; d < 64; ++d)
        dot += xs[r][d] * __uint_as_float(((unsigned int)Wlbf[dp * 64 + d]) << 16);
    xhid[b * 1024 + h * 64 + dp] = f2bf(dot);
}

// ---------------------------------------------------------------------------
// K7: fill attn_out (2097152 fp32) with 1.0f — LAST, after scratch use ends
// ---------------------------------------------------------------------------
__global__ __launch_bounds__(256) void k_ones(float4* __restrict__ attn_out)
{
    int idx = blockIdx.x * 256 + threadIdx.x;   // 0..524287
    float4 ones = {1.f, 1.f, 1.f, 1.f};
    attn_out[idx] = ones;
}

// ---------------------------------------------------------------------------
// Buffers are fp32 (reference dtypes). Output 0 = 2097152 floats (8 MiB) of
// exact 1.0 — doubles as scratch; k_ones runs last. d_ws untouched.
// Byte layout in d_out[0 .. 8388608):
//   part    [0,       2097152)  f32 [8][128][512]   (dead after combine)
//   Wxbf    [2097152, 4194304)  bf16 (1024,1024)
//   Wkbf    [4194304, 5242880)  bf16 (1024,512)
//   Wobf    [5242880, 6291456)  bf16 (512,1024)
//   Wlbf    [6291456, 6299648)  bf16 (64,64)
//   xnbf    [6299648, 6561792)  bf16 (128,1024)
//   ksumbf  [6561792, 6692864)  bf16 (128,512)
//   xq      [6692864, 7217152)  f32  (128,1024)
//   ab      [7217152, 7217664)  f32  128
//   concat  [7217664, 7741952)  bf16 (256,1024): rows 0-127 outf, 128-255 xhid
// Outputs 1,2: fp32 at element offset 2097152 (byte 8388608), (256,512) flat.
// ---------------------------------------------------------------------------
extern "C" void kernel_launch(void* const* d_in, const int* in_sizes, int n_in,
                              void* d_out, int out_size, void* d_ws, size_t ws_size,
                              hipStream_t stream) {
    (void)d_ws; (void)ws_size; (void)in_sizes; (void)n_in; (void)out_size;
    const float* x  = (const float*)d_in[0];
    const float* kk = (const float*)d_in[1];
    const float* g1 = (const float*)d_in[2];
    const float* b1 = (const float*)d_in[3];
    const float* Wx = (const float*)d_in[4];
    const float* bx = (const float*)d_in[5];
    const float* Wk = (const float*)d_in[6];
    const float* bk = (const float*)d_in[7];
    const float* g2 = (const float*)d_in[8];
    const float* b2 = (const float*)d_in[9];
    const float* Wl = (const float*)d_in[10];
    const float* bl = (const float*)d_in[11];
    const float* Wo = (const float*)d_in[12];
    const float* bo = (const float*)d_in[13];

    char* ob = (char*)d_out;
    float*          part   = (float*)(ob + 0);
    unsigned short* Wxbf   = (unsigned short*)(ob + 2097152);
    unsigned short* Wkbf   = (unsigned short*)(ob + 4194304);
    unsigned short* Wobf   = (unsigned short*)(ob + 5242880);
    unsigned short* Wlbf   = (unsigned short*)(ob + 6291456);
    unsigned short* xnbf   = (unsigned short*)(ob + 6299648);
    unsigned short* ksumbf = (unsigned short*)(ob + 6561792);
    float*          xq     = (float*)(ob + 6692864);
    float*          ab     = (float*)(ob + 7217152);
    unsigned short* concat = (unsigned short*)(ob + 7217664);
    float*          out12  = (float*)d_out + 2097152;

    // 1) big streaming reduce over k -> part  (268 MB, the dominant cost)
    k_reduce<<<1024, 256, 0, stream>>>(kk, part);
    // 2) weights fp32 -> bf16
    k_w2bf<<<2052, 256, 0, stream>>>(Wx, Wk, Wo, Wl, Wxbf, Wkbf, Wobf, Wlbf);
    // 3) BN1 -> xn bf16, combine part -> ksum bf16
    k_bn1_combine<<<36, 256, 0, stream>>>(x, g1, b1, part, xnbf, ksumbf);
    // 4) xq = xn @ Wx^T + bx   (128,1024,K=1024) -> fp32
    k_mfma<float><<<128, 256, 0, stream>>>(xnbf, 1024, Wxbf, 1024, bx, 1.f, xq, 1024, 64, 1024);
    // 5) outf = ksum @ Wk^T + 1024*bk   (128,1024,K=512) -> bf16 concat rows 0-127
    k_mfma<unsigned short><<<128, 256, 0, stream>>>(ksumbf, 512, Wkbf, 512, bk, 1024.f, concat, 1024, 64, 512);
    // 6) BN2 stats
    k_bn2<<<64, 256, 0, stream>>>(xq, g2, b2, ab);
    // 7) latent -> x_hid bf16, concat rows 128-255
    k_latent<<<512, 256, 0, stream>>>(xq, ab, Wlbf, bl, concat + 131072);
    // 8) [outf; xhid] (256,1024) @ Wo^T + bo -> outputs 1,2 (fp32)
    k_mfma<float><<<128, 256, 0, stream>>>(concat, 1024, Wobf, 1024, bo, 1.f, out12, 512, 32, 1024);
    // 9) attn_out = 1.0f over the whole 8 MiB scratch region
    k_ones<<<2048, 256, 0, stream>>>((float4*)d_out);
}

// Round 4
// 427.444 us; speedup vs baseline: 1.0440x; 1.0440x over previous
//
#include <hip/hip_runtime.h>

typedef __attribute__((ext_vector_type(8))) short short8;
typedef __attribute__((ext_vector_type(4))) float floatx4;

__device__ __forceinline__ unsigned short f2bf(float f) {
    unsigned int x = __float_as_uint(f);
    x = x + 0x7FFFu + ((x >> 16) & 1u);   // RNE
    return (unsigned short)(x >> 16);
}

// ---------------------------------------------------------------------------
// MFMA 16x16 tile GEMM helper: C(M,N) = A(M,K) * B(N,K)^T + bscale*bias(N).
// A,B bf16 row-major K-contiguous. One wave per tile.
// A frag A[m=lane&15][k=q*8+j]; B frag B[n=lane&15][k=q*8+j];
// D: col=lane&15, row=q*4+r (learn_hip m89/m91). bias fp32.
// ---------------------------------------------------------------------------
template <typename OutT>
__device__ __forceinline__ void gemm_tile(
    const unsigned short* __restrict__ A, int lda,
    const unsigned short* __restrict__ B, int ldb,
    const float* __restrict__ bias, float bscale,
    OutT* __restrict__ C, int ldc, int tilesN, int K, int wave, int lane)
{
    int tm = wave / tilesN, tn = wave % tilesN;
    int mn = lane & 15, q = lane >> 4;
    const short8* ap = (const short8*)(A + (size_t)(tm * 16 + mn) * lda + q * 8);
    const short8* bp = (const short8*)(B + (size_t)(tn * 16 + mn) * ldb + q * 8);
    floatx4 acc = {0.f, 0.f, 0.f, 0.f};
    #pragma unroll 4
    for (int k = 0; k < K; k += 32) {
        short8 a = *ap; ap += 4;
        short8 b = *bp; bp += 4;
        acc = __builtin_amdgcn_mfma_f32_16x16x32_bf16(a, b, acc, 0, 0, 0);
    }
    int col = tn * 16 + mn;
    float bv = bias[col] * bscale;
    #pragma unroll
    for (int r = 0; r < 4; ++r) {
        int row = tm * 16 + q * 4 + r;
        float v = acc[r] + bv;
        OutT* dst = C + (size_t)row * ldc + col;
        if constexpr (sizeof(OutT) == 2) *dst = (OutT)f2bf(v);
        else                             *dst = (OutT)v;
    }
}

// ---------------------------------------------------------------------------
// K1 MEGA: all input-independent-order work in one launch.
//  blocks [0,1024):    ksum partials over n. k:(128,1024,512) f32 stream.
//                      b=blk>>3, c=blk&7 (chunk of 128 n-rows). part[c][b][j].
//  blocks [1024,3076): weights f32 -> bf16 (Wx 1M, Wk 512K, Wo 512K, Wl 4K).
//  blocks [3076,5124): attn_out (output 0) = 1.0f, 2097152 floats.
//  blocks [5124,5128): BN1(x) -> xnbf bf16.
// ---------------------------------------------------------------------------
__global__ __launch_bounds__(256) void k_mega(
    const float* __restrict__ kk, float* __restrict__ part,
    const float* __restrict__ Wx, const float* __restrict__ Wk,
    const float* __restrict__ Wo, const float* __restrict__ Wl,
    unsigned short* __restrict__ Wxbf, unsigned short* __restrict__ Wkbf,
    unsigned short* __restrict__ Wobf, unsigned short* __restrict__ Wlbf,
    float4* __restrict__ attn_out,
    const float* __restrict__ x, const float* __restrict__ g1,
    const float* __restrict__ b1, unsigned short* __restrict__ xnbf)
{
    int blk = blockIdx.x, tid = threadIdx.x;
    if (blk < 1024) {
        int b = blk >> 3, c = blk & 7;
        int f4 = tid & 127;
        int rh = tid >> 7;
        const float4* base = (const float4*)kk
            + ((size_t)(b * 1024 + c * 128 + rh) * 128 + f4);
        float4 acc = {0.f, 0.f, 0.f, 0.f};
        #pragma unroll 8
        for (int it = 0; it < 64; ++it) {
            float4 v = base[(size_t)it * 256];
            acc.x += v.x; acc.y += v.y; acc.z += v.z; acc.w += v.w;
        }
        __shared__ float red[2][512];
        red[rh][f4 * 4 + 0] = acc.x;
        red[rh][f4 * 4 + 1] = acc.y;
        red[rh][f4 * 4 + 2] = acc.z;
        red[rh][f4 * 4 + 3] = acc.w;
        __syncthreads();
        for (int j = tid; j < 512; j += 256)
            part[((size_t)(c * 128 + b) << 9) + j] = red[0][j] + red[1][j];
    } else if (blk < 3076) {
        int f = (blk - 1024) * 256 + tid;   // float4 index, < 525312
        const float* src; unsigned short* dst; int off;
        if (f < 262144)      { src = Wx; dst = Wxbf; off = f; }
        else if (f < 393216) { src = Wk; dst = Wkbf; off = f - 262144; }
        else if (f < 524288) { src = Wo; dst = Wobf; off = f - 393216; }
        else                 { src = Wl; dst = Wlbf; off = f - 524288; }
        float4 v = ((const float4*)src)[off];
        uint2 o;
        o.x = (unsigned int)f2bf(v.x) | ((unsigned int)f2bf(v.y) << 16);
        o.y = (unsigned int)f2bf(v.z) | ((unsigned int)f2bf(v.w) << 16);
        *(uint2*)(dst + off * 4) = o;
    } else if (blk < 5124) {
        int idx = (blk - 3076) * 256 + tid;   // < 524288 float4
        float4 ones = {1.f, 1.f, 1.f, 1.f};
        attn_out[idx] = ones;
    } else {
        int c = (blk - 5124) * 256 + tid;
        float s = 0.f, ss = 0.f;
        #pragma unroll 8
        for (int b = 0; b < 128; ++b) {
            float v = x[b * 1024 + c];
            s += v; ss += v * v;
        }
        float m  = s * (1.f / 128.f);
        float va = ss * (1.f / 128.f) - m * m;
        float rs = rsqrtf(va + 1e-5f);
        float a  = rs * g1[c];
        float b2 = b1[c] - m * a;
        #pragma unroll 8
        for (int b = 0; b < 128; ++b)
            xnbf[b * 1024 + c] = f2bf(x[b * 1024 + c] * a + b2);
    }
}

// ---------------------------------------------------------------------------
// K2: combine ksum partials (8 chunks) -> ksum bf16 (128,512)
// ---------------------------------------------------------------------------
__global__ __launch_bounds__(256) void k_combine(
    const float* __restrict__ part, unsigned short* __restrict__ ksumbf)
{
    int idx = blockIdx.x * 256 + threadIdx.x;   // 0..8191
    int b = idx >> 6;
    int j0 = (idx & 63) * 8;
    float s[8];
    #pragma unroll
    for (int u = 0; u < 8; ++u) s[u] = 0.f;
    #pragma unroll
    for (int c = 0; c < 8; ++c) {
        const float4* p = (const float4*)(part + ((size_t)(c * 128 + b) << 9) + j0);
        float4 a0 = p[0], a1 = p[1];
        s[0] += a0.x; s[1] += a0.y; s[2] += a0.z; s[3] += a0.w;
        s[4] += a1.x; s[5] += a1.y; s[6] += a1.z; s[7] += a1.w;
    }
    uint4 v;
    v.x = (unsigned int)f2bf(s[0]) | ((unsigned int)f2bf(s[1]) << 16);
    v.y = (unsigned int)f2bf(s[2]) | ((unsigned int)f2bf(s[3]) << 16);
    v.z = (unsigned int)f2bf(s[4]) | ((unsigned int)f2bf(s[5]) << 16);
    v.w = (unsigned int)f2bf(s[6]) | ((unsigned int)f2bf(s[7]) << 16);
    *(uint4*)(ksumbf + b * 512 + j0) = v;
}

// ---------------------------------------------------------------------------
// K3: dual GEMM — blocks [0,128): xq = xn @ Wx^T + bx (128,1024,K=1024)->f32
//                 blocks [128,256): outf = ksum @ Wk^T + 1024*bk -> bf16
// ---------------------------------------------------------------------------
__global__ __launch_bounds__(256) void k_dual_gemm(
    const unsigned short* __restrict__ xnbf, const unsigned short* __restrict__ Wxbf,
    const float* __restrict__ bx, float* __restrict__ xq,
    const unsigned short* __restrict__ ksumbf, const unsigned short* __restrict__ Wkbf,
    const float* __restrict__ bk, unsigned short* __restrict__ concat)
{
    int blk = blockIdx.x, tid = threadIdx.x, lane = tid & 63;
    if (blk < 128) {
        int wave = (blk * 256 + tid) >> 6;
        gemm_tile<float>(xnbf, 1024, Wxbf, 1024, bx, 1.f, xq, 1024, 64, 1024, wave, lane);
    } else {
        int wave = ((blk - 128) * 256 + tid) >> 6;
        gemm_tile<unsigned short>(ksumbf, 512, Wkbf, 512, bk, 1024.f, concat, 1024, 64, 512, wave, lane);
    }
}

// ---------------------------------------------------------------------------
// K4: BN2 stats over xq viewed as (H*B, 64): scale ab[d], shift ab[64+d]
// ---------------------------------------------------------------------------
__global__ __launch_bounds__(256) void k_bn2(
    const float* __restrict__ xq, const float* __restrict__ g2,
    const float* __restrict__ b2, float* __restrict__ ab)
{
    int d = blockIdx.x, tid = threadIdx.x;
    float s = 0.f, ss = 0.f;
    for (int e = tid; e < 2048; e += 256) {
        int b = e >> 4, h = e & 15;
        float v = xq[b * 1024 + h * 64 + d];
        s += v; ss += v * v;
    }
    __shared__ float r1[256], r2[256];
    r1[tid] = s; r2[tid] = ss;
    __syncthreads();
    for (int off = 128; off; off >>= 1) {
        if (tid < off) { r1[tid] += r1[tid + off]; r2[tid] += r2[tid + off]; }
        __syncthreads();
    }
    if (tid == 0) {
        float m  = r1[0] * (1.f / 2048.f);
        float va = r2[0] * (1.f / 2048.f) - m * m;
        float rs = rsqrtf(va + 1e-5f);
        float a  = rs * g2[d];
        ab[d] = a;
        ab[64 + d] = b2[d] - m * a;
    }
}

// ---------------------------------------------------------------------------
// K5: latent = BN2(xq) @ Wlin^T + blin -> concat rows 128-255 (bf16)
// ---------------------------------------------------------------------------
__global__ __launch_bounds__(256) void k_latent(
    const float* __restrict__ xq, const float* __restrict__ ab,
    const unsigned short* __restrict__ Wlbf, const float* __restrict__ bl,
    unsigned short* __restrict__ xhid)
{
    int tid = threadIdx.x;
    int r = tid >> 6, dp = tid & 63;
    int row = blockIdx.x * 4 + r;     // row = h*128 + b
    int h = row >> 7, b = row & 127;
    __shared__ float xs[4][64];
    xs[r][dp] = xq[b * 1024 + h * 64 + dp] * ab[dp] + ab[64 + dp];
    __syncthreads();
    float dot = bl[dp];
    #pragma unroll 16
    for (int d = 0; d < 64; ++d)
        dot += xs[r][d] * __uint_as_float(((unsigned int)Wlbf[dp * 64 + d]) << 16);
    xhid[b * 1024 + h * 64 + dp] = f2bf(dot);
}

// ---------------------------------------------------------------------------
// K6: final GEMM — [outf; xhid] (256,1024) @ Wo^T + bo -> outputs 1,2 (fp32)
// ---------------------------------------------------------------------------
__global__ __launch_bounds__(256) void k_final_gemm(
    const unsigned short* __restrict__ concat, const unsigned short* __restrict__ Wobf,
    const float* __restrict__ bo, float* __restrict__ out12)
{
    int wave = (blockIdx.x * 256 + threadIdx.x) >> 6;
    gemm_tile<float>(concat, 1024, Wobf, 1024, bo, 1.f, out12, 512, 32, 1024,
                     wave, threadIdx.x & 63);
}

// ---------------------------------------------------------------------------
// Scratch now lives in d_ws (harness poison shows ws_size >= 1 GiB).
// ws byte layout:
//   part    [0,       2097152)  f32 [8][128][512]
//   Wxbf    [2097152, 4194304)  bf16 (1024,1024)
//   Wkbf    [4194304, 5242880)  bf16 (1024,512)
//   Wobf    [5242880, 6291456)  bf16 (512,1024)
//   Wlbf    [6291456, 6299648)  bf16 (64,64)
//   xnbf    [6299648, 6561792)  bf16 (128,1024)
//   ksumbf  [6561792, 6692864)  bf16 (128,512)
//   xq      [6692864, 7217152)  f32  (128,1024)
//   ab      [7217152, 7217664)  f32  128
//   concat  [7217664, 7741952)  bf16 (256,1024): rows 0-127 outf, 128-255 xhid
// d_out: [0, 2097152) floats = attn ones; [2097152, 2228224) = out2|out3.
// ---------------------------------------------------------------------------
extern "C" void kernel_launch(void* const* d_in, const int* in_sizes, int n_in,
                              void* d_out, int out_size, void* d_ws, size_t ws_size,
                              hipStream_t stream) {
    (void)in_sizes; (void)n_in; (void)out_size; (void)ws_size;
    const float* x  = (const float*)d_in[0];
    const float* kk = (const float*)d_in[1];
    const float* g1 = (const float*)d_in[2];
    const float* b1 = (const float*)d_in[3];
    const float* Wx = (const float*)d_in[4];
    const float* bx = (const float*)d_in[5];
    const float* Wk = (const float*)d_in[6];
    const float* bk = (const float*)d_in[7];
    const float* g2 = (const float*)d_in[8];
    const float* b2 = (const float*)d_in[9];
    const float* Wl = (const float*)d_in[10];
    const float* bl = (const float*)d_in[11];
    const float* Wo = (const float*)d_in[12];
    const float* bo = (const float*)d_in[13];

    char* ws = (char*)d_ws;
    float*          part   = (float*)(ws + 0);
    unsigned short* Wxbf   = (unsigned short*)(ws + 2097152);
    unsigned short* Wkbf   = (unsigned short*)(ws + 4194304);
    unsigned short* Wobf   = (unsigned short*)(ws + 5242880);
    unsigned short* Wlbf   = (unsigned short*)(ws + 6291456);
    unsigned short* xnbf   = (unsigned short*)(ws + 6299648);
    unsigned short* ksumbf = (unsigned short*)(ws + 6561792);
    float*          xq     = (float*)(ws + 6692864);
    float*          ab     = (float*)(ws + 7217152);
    unsigned short* concat = (unsigned short*)(ws + 7217664);
    float*          out12  = (float*)d_out + 2097152;

    // 1) everything with no intra-pipeline deps, one launch
    k_mega<<<5128, 256, 0, stream>>>(kk, part, Wx, Wk, Wo, Wl,
                                     Wxbf, Wkbf, Wobf, Wlbf,
                                     (float4*)d_out, x, g1, b1, xnbf);
    // 2) part -> ksum bf16
    k_combine<<<32, 256, 0, stream>>>(part, ksumbf);
    // 3) xq GEMM + outf GEMM fused
    k_dual_gemm<<<256, 256, 0, stream>>>(xnbf, Wxbf, bx, xq, ksumbf, Wkbf, bk, concat);
    // 4) BN2 stats
    k_bn2<<<64, 256, 0, stream>>>(xq, g2, b2, ab);
    // 5) latent -> concat rows 128-255
    k_latent<<<512, 256, 0, stream>>>(xq, ab, Wlbf, bl, concat + 131072);
    // 6) final GEMM -> outputs 1,2
    k_final_gemm<<<128, 256, 0, stream>>>(concat, Wobf, bo, out12);
}

// Round 5
// 426.915 us; speedup vs baseline: 1.0453x; 1.0012x over previous
//
#include <hip/hip_runtime.h>

typedef __attribute__((ext_vector_type(8))) short short8;
typedef __attribute__((ext_vector_type(4))) float floatx4;

__device__ __forceinline__ unsigned short f2bf(float f) {
    unsigned int x = __float_as_uint(f);
    x = x + 0x7FFFu + ((x >> 16) & 1u);   // RNE
    return (unsigned short)(x >> 16);
}

// ---------------------------------------------------------------------------
// MFMA 16x16 tile GEMM helper: C(M,N) = A(M,K) * B(N,K)^T + bscale*bias(N).
// A,B bf16 row-major K-contiguous. One wave per tile.
// A frag A[m=lane&15][k=q*8+j]; B frag B[n=lane&15][k=q*8+j];
// D: col=lane&15, row=q*4+r (learn_hip m89/m91). bias fp32.
// ---------------------------------------------------------------------------
template <typename OutT>
__device__ __forceinline__ void gemm_tile(
    const unsigned short* __restrict__ A, int lda,
    const unsigned short* __restrict__ B, int ldb,
    const float* __restrict__ bias, float bscale,
    OutT* __restrict__ C, int ldc, int tilesN, int K, int wave, int lane)
{
    int tm = wave / tilesN, tn = wave % tilesN;
    int mn = lane & 15, q = lane >> 4;
    const short8* ap = (const short8*)(A + (size_t)(tm * 16 + mn) * lda + q * 8);
    const short8* bp = (const short8*)(B + (size_t)(tn * 16 + mn) * ldb + q * 8);
    floatx4 acc = {0.f, 0.f, 0.f, 0.f};
    #pragma unroll 4
    for (int k = 0; k < K; k += 32) {
        short8 a = *ap; ap += 4;
        short8 b = *bp; bp += 4;
        acc = __builtin_amdgcn_mfma_f32_16x16x32_bf16(a, b, acc, 0, 0, 0);
    }
    int col = tn * 16 + mn;
    float bv = bias[col] * bscale;
    #pragma unroll
    for (int r = 0; r < 4; ++r) {
        int row = tm * 16 + q * 4 + r;
        float v = acc[r] + bv;
        OutT* dst = C + (size_t)row * ldc + col;
        if constexpr (sizeof(OutT) == 2) *dst = (OutT)f2bf(v);
        else                             *dst = (OutT)v;
    }
}

// ---------------------------------------------------------------------------
// K1 MEGA: all input-independent-order work in one launch.
//  blocks [0,1024):    ksum partials over n. k:(128,1024,512) f32 stream.
//  blocks [1024,3076): weights f32 -> bf16.
//  blocks [3076,5124): attn_out (output 0) = 1.0f.
//  blocks [5124,5128): BN1(x) -> xnbf bf16.
// ---------------------------------------------------------------------------
__global__ __launch_bounds__(256) void k_mega(
    const float* __restrict__ kk, float* __restrict__ part,
    const float* __restrict__ Wx, const float* __restrict__ Wk,
    const float* __restrict__ Wo, const float* __restrict__ Wl,
    unsigned short* __restrict__ Wxbf, unsigned short* __restrict__ Wkbf,
    unsigned short* __restrict__ Wobf, unsigned short* __restrict__ Wlbf,
    float4* __restrict__ attn_out,
    const float* __restrict__ x, const float* __restrict__ g1,
    const float* __restrict__ b1, unsigned short* __restrict__ xnbf)
{
    int blk = blockIdx.x, tid = threadIdx.x;
    if (blk < 1024) {
        int b = blk >> 3, c = blk & 7;
        int f4 = tid & 127;
        int rh = tid >> 7;
        const float4* base = (const float4*)kk
            + ((size_t)(b * 1024 + c * 128 + rh) * 128 + f4);
        float4 acc = {0.f, 0.f, 0.f, 0.f};
        #pragma unroll 8
        for (int it = 0; it < 64; ++it) {
            float4 v = base[(size_t)it * 256];
            acc.x += v.x; acc.y += v.y; acc.z += v.z; acc.w += v.w;
        }
        __shared__ float red[2][512];
        red[rh][f4 * 4 + 0] = acc.x;
        red[rh][f4 * 4 + 1] = acc.y;
        red[rh][f4 * 4 + 2] = acc.z;
        red[rh][f4 * 4 + 3] = acc.w;
        __syncthreads();
        for (int j = tid; j < 512; j += 256)
            part[((size_t)(c * 128 + b) << 9) + j] = red[0][j] + red[1][j];
    } else if (blk < 3076) {
        int f = (blk - 1024) * 256 + tid;   // float4 index, < 525312
        const float* src; unsigned short* dst; int off;
        if (f < 262144)      { src = Wx; dst = Wxbf; off = f; }
        else if (f < 393216) { src = Wk; dst = Wkbf; off = f - 262144; }
        else if (f < 524288) { src = Wo; dst = Wobf; off = f - 393216; }
        else                 { src = Wl; dst = Wlbf; off = f - 524288; }
        float4 v = ((const float4*)src)[off];
        uint2 o;
        o.x = (unsigned int)f2bf(v.x) | ((unsigned int)f2bf(v.y) << 16);
        o.y = (unsigned int)f2bf(v.z) | ((unsigned int)f2bf(v.w) << 16);
        *(uint2*)(dst + off * 4) = o;
    } else if (blk < 5124) {
        int idx = (blk - 3076) * 256 + tid;   // < 524288 float4
        float4 ones = {1.f, 1.f, 1.f, 1.f};
        attn_out[idx] = ones;
    } else {
        int c = (blk - 5124) * 256 + tid;
        float s = 0.f, ss = 0.f;
        #pragma unroll 8
        for (int b = 0; b < 128; ++b) {
            float v = x[b * 1024 + c];
            s += v; ss += v * v;
        }
        float m  = s * (1.f / 128.f);
        float va = ss * (1.f / 128.f) - m * m;
        float rs = rsqrtf(va + 1e-5f);
        float a  = rs * g1[c];
        float b2 = b1[c] - m * a;
        #pragma unroll 8
        for (int b = 0; b < 128; ++b)
            xnbf[b * 1024 + c] = f2bf(x[b * 1024 + c] * a + b2);
    }
}

// ---------------------------------------------------------------------------
// K2: blocks [0,32):   combine ksum partials -> ksumbf bf16 (128,512)
//     blocks [32,160): xq = xn @ Wx^T + bx (128,1024,K=1024) -> f32
// (both consume only K1 outputs — no intra-kernel dependency)
// ---------------------------------------------------------------------------
__global__ __launch_bounds__(256) void k_combine_xq(
    const float* __restrict__ part, unsigned short* __restrict__ ksumbf,
    const unsigned short* __restrict__ xnbf, const unsigned short* __restrict__ Wxbf,
    const float* __restrict__ bx, float* __restrict__ xq)
{
    int blk = blockIdx.x, tid = threadIdx.x;
    if (blk < 32) {
        int idx = blk * 256 + tid;   // 0..8191
        int b = idx >> 6;
        int j0 = (idx & 63) * 8;
        float s[8];
        #pragma unroll
        for (int u = 0; u < 8; ++u) s[u] = 0.f;
        #pragma unroll
        for (int c = 0; c < 8; ++c) {
            const float4* p = (const float4*)(part + ((size_t)(c * 128 + b) << 9) + j0);
            float4 a0 = p[0], a1 = p[1];
            s[0] += a0.x; s[1] += a0.y; s[2] += a0.z; s[3] += a0.w;
            s[4] += a1.x; s[5] += a1.y; s[6] += a1.z; s[7] += a1.w;
        }
        uint4 v;
        v.x = (unsigned int)f2bf(s[0]) | ((unsigned int)f2bf(s[1]) << 16);
        v.y = (unsigned int)f2bf(s[2]) | ((unsigned int)f2bf(s[3]) << 16);
        v.z = (unsigned int)f2bf(s[4]) | ((unsigned int)f2bf(s[5]) << 16);
        v.w = (unsigned int)f2bf(s[6]) | ((unsigned int)f2bf(s[7]) << 16);
        *(uint4*)(ksumbf + b * 512 + j0) = v;
    } else {
        int wave = ((blk - 32) * 256 + tid) >> 6;
        gemm_tile<float>(xnbf, 1024, Wxbf, 1024, bx, 1.f, xq, 1024, 64, 1024,
                         wave, tid & 63);
    }
}

// ---------------------------------------------------------------------------
// K3: blocks [0,64):   BN2 stats over xq (reads xq from K2)
//     blocks [64,192): outf = ksum @ Wk^T + 1024*bk -> bf16 concat rows 0-127
// (bn2 needs xq; outf needs ksumbf — both from K2, independent of each other)
// ---------------------------------------------------------------------------
__global__ __launch_bounds__(256) void k_bn2_outf(
    const float* __restrict__ xq, const float* __restrict__ g2,
    const float* __restrict__ b2, float* __restrict__ ab,
    const unsigned short* __restrict__ ksumbf, const unsigned short* __restrict__ Wkbf,
    const float* __restrict__ bk, unsigned short* __restrict__ concat)
{
    int blk = blockIdx.x, tid = threadIdx.x;
    if (blk < 64) {
        int d = blk;
        float s = 0.f, ss = 0.f;
        for (int e = tid; e < 2048; e += 256) {
            int b = e >> 4, h = e & 15;
            float v = xq[b * 1024 + h * 64 + d];
            s += v; ss += v * v;
        }
        __shared__ float r1[256], r2[256];
        r1[tid] = s; r2[tid] = ss;
        __syncthreads();
        for (int off = 128; off; off >>= 1) {
            if (tid < off) { r1[tid] += r1[tid + off]; r2[tid] += r2[tid + off]; }
            __syncthreads();
        }
        if (tid == 0) {
            float m  = r1[0] * (1.f / 2048.f);
            float va = r2[0] * (1.f / 2048.f) - m * m;
            float rs = rsqrtf(va + 1e-5f);
            float a  = rs * g2[d];
            ab[d] = a;
            ab[64 + d] = b2[d] - m * a;
        }
    } else {
        int wave = ((blk - 64) * 256 + tid) >> 6;
        gemm_tile<unsigned short>(ksumbf, 512, Wkbf, 512, bk, 1024.f, concat,
                                  1024, 64, 512, wave, tid & 63);
    }
}

// ---------------------------------------------------------------------------
// K4: latent = BN2(xq) @ Wlin^T + blin -> concat rows 128-255 (bf16)
// ---------------------------------------------------------------------------
__global__ __launch_bounds__(256) void k_latent(
    const float* __restrict__ xq, const float* __restrict__ ab,
    const unsigned short* __restrict__ Wlbf, const float* __restrict__ bl,
    unsigned short* __restrict__ xhid)
{
    int tid = threadIdx.x;
    int r = tid >> 6, dp = tid & 63;
    int row = blockIdx.x * 4 + r;     // row = h*128 + b
    int h = row >> 7, b = row & 127;
    __shared__ float xs[4][64];
    xs[r][dp] = xq[b * 1024 + h * 64 + dp] * ab[dp] + ab[64 + dp];
    __syncthreads();
    float dot = bl[dp];
    #pragma unroll 16
    for (int d = 0; d < 64; ++d)
        dot += xs[r][d] * __uint_as_float(((unsigned int)Wlbf[dp * 64 + d]) << 16);
    xhid[b * 1024 + h * 64 + dp] = f2bf(dot);
}

// ---------------------------------------------------------------------------
// K5: final GEMM — [outf; xhid] (256,1024) @ Wo^T + bo -> outputs 1,2 (fp32)
// ---------------------------------------------------------------------------
__global__ __launch_bounds__(256) void k_final_gemm(
    const unsigned short* __restrict__ concat, const unsigned short* __restrict__ Wobf,
    const float* __restrict__ bo, float* __restrict__ out12)
{
    int wave = (blockIdx.x * 256 + threadIdx.x) >> 6;
    gemm_tile<float>(concat, 1024, Wobf, 1024, bo, 1.f, out12, 512, 32, 1024,
                     wave, threadIdx.x & 63);
}

// ---------------------------------------------------------------------------
// ws byte layout (ws_size >= 1 GiB per harness poison dispatches):
//   part    [0,       2097152)  f32 [8][128][512]
//   Wxbf    [2097152, 4194304)  bf16 (1024,1024)
//   Wkbf    [4194304, 5242880)  bf16 (1024,512)
//   Wobf    [5242880, 6291456)  bf16 (512,1024)
//   Wlbf    [6291456, 6299648)  bf16 (64,64)
//   xnbf    [6299648, 6561792)  bf16 (128,1024)
//   ksumbf  [6561792, 6692864)  bf16 (128,512)
//   xq      [6692864, 7217152)  f32  (128,1024)
//   ab      [7217152, 7217664)  f32  128
//   concat  [7217664, 7741952)  bf16 (256,1024): rows 0-127 outf, 128-255 xhid
// d_out: [0, 2097152) floats = attn ones; then out2|out3 (256,512) fp32.
// Launch chain (5 = dependency-depth floor): mega -> {combine,xq} ->
// {bn2,outf} -> latent -> final.
// ---------------------------------------------------------------------------
extern "C" void kernel_launch(void* const* d_in, const int* in_sizes, int n_in,
                              void* d_out, int out_size, void* d_ws, size_t ws_size,
                              hipStream_t stream) {
    (void)in_sizes; (void)n_in; (void)out_size; (void)ws_size;
    const float* x  = (const float*)d_in[0];
    const float* kk = (const float*)d_in[1];
    const float* g1 = (const float*)d_in[2];
    const float* b1 = (const float*)d_in[3];
    const float* Wx = (const float*)d_in[4];
    const float* bx = (const float*)d_in[5];
    const float* Wk = (const float*)d_in[6];
    const float* bk = (const float*)d_in[7];
    const float* g2 = (const float*)d_in[8];
    const float* b2 = (const float*)d_in[9];
    const float* Wl = (const float*)d_in[10];
    const float* bl = (const float*)d_in[11];
    const float* Wo = (const float*)d_in[12];
    const float* bo = (const float*)d_in[13];

    char* ws = (char*)d_ws;
    float*          part   = (float*)(ws + 0);
    unsigned short* Wxbf   = (unsigned short*)(ws + 2097152);
    unsigned short* Wkbf   = (unsigned short*)(ws + 4194304);
    unsigned short* Wobf   = (unsigned short*)(ws + 5242880);
    unsigned short* Wlbf   = (unsigned short*)(ws + 6291456);
    unsigned short* xnbf   = (unsigned short*)(ws + 6299648);
    unsigned short* ksumbf = (unsigned short*)(ws + 6561792);
    float*          xq     = (float*)(ws + 6692864);
    float*          ab     = (float*)(ws + 7217152);
    unsigned short* concat = (unsigned short*)(ws + 7217664);
    float*          out12  = (float*)d_out + 2097152;

    k_mega<<<5128, 256, 0, stream>>>(kk, part, Wx, Wk, Wo, Wl,
                                     Wxbf, Wkbf, Wobf, Wlbf,
                                     (float4*)d_out, x, g1, b1, xnbf);
    k_combine_xq<<<160, 256, 0, stream>>>(part, ksumbf, xnbf, Wxbf, bx, xq);
    k_bn2_outf<<<192, 256, 0, stream>>>(xq, g2, b2, ab, ksumbf, Wkbf, bk, concat);
    k_latent<<<512, 256, 0, stream>>>(xq, ab, Wlbf, bl, concat + 131072);
    k_final_gemm<<<128, 256, 0, stream>>>(concat, Wobf, bo, out12);
}